// Round 1
// baseline (107.633 us; speedup 1.0000x reference)
//
#include <hip/hip_runtime.h>
#include <math.h>

#define TT 24
#define SS 200
#define NN 4800           // TT*SS
#define CIN 8
#define CW 32
#define NSC (SS*CW)       // 6400

// ---------------- degree^{-1/2} ----------------
__global__ void k_dinv(const float* __restrict__ At, const float* __restrict__ As,
                       float* __restrict__ dinv_t, float* __restrict__ dinv_s) {
    int tid = threadIdx.x;
    if (tid < TT) {
        float sum = 0.f;
        for (int j = 0; j < TT; ++j) sum += At[tid*TT + j];
        dinv_t[tid] = 1.0f / sqrtf(sum);
    } else if (tid < TT + SS) {
        int i = tid - TT;
        float sum = 0.f;
        for (int j = 0; j < SS; ++j) sum += As[i*SS + j];
        dinv_s[i] = 1.0f / sqrtf(sum);
    }
}

// ---------------- normalized adjacencies ----------------
__global__ void k_norm(const float* __restrict__ At, const float* __restrict__ As,
                       const float* __restrict__ dinv_t, const float* __restrict__ dinv_s,
                       float* __restrict__ At_n, float* __restrict__ As_n) {
    int idx = blockIdx.x * 256 + threadIdx.x;
    if (idx < TT*TT) {
        int i = idx / TT, j = idx % TT;
        At_n[idx] = At[idx] * dinv_t[i] * dinv_t[j] * 0.5f;
    } else if (idx < TT*TT + SS*SS) {
        int e = idx - TT*TT;
        int i = e / SS, j = e % SS;
        As_n[e] = As[e] * dinv_s[i] * dinv_s[j] * 0.5f;
    }
}

// ---------------- x = x_in @ W_first + b_first ----------------
__global__ void k_first(const float* __restrict__ xin, const float* __restrict__ Wf,
                        const float* __restrict__ bf, float* __restrict__ x) {
    int idx = blockIdx.x * 256 + threadIdx.x;   // n*32 + c, exact 153600
    int n = idx >> 5, c = idx & 31;
    float acc = bf[c];
    #pragma unroll
    for (int i = 0; i < CIN; ++i) acc += xin[n*CIN + i] * Wf[i*CW + c];
    x[idx] = acc;
}

// ---------------- y[t,s,c] = sum_{s'} As_n[s,s'] p[t,s',c] ----------------
__global__ void k_spatial(const float* __restrict__ As_n, const float* __restrict__ p,
                          float* __restrict__ y) {
    int idx = blockIdx.x * 256 + threadIdx.x;   // exact 153600
    int t = idx / NSC;
    int rem = idx - t*NSC;
    int s = rem >> 5, c = rem & 31;
    const float* prow = p + t*NSC + c;
    const float* arow = As_n + s*SS;
    float acc = 0.f;
    #pragma unroll 4
    for (int sp = 0; sp < SS; ++sp) acc += arow[sp] * prow[sp*CW];
    y[idx] = acc;
}

// ---------------- p_out = s0 p + s1 y + s2 Tp(p) + s3 Tp(y) ----------------
__global__ void k_temporal(const float* __restrict__ At_n, const float* __restrict__ p,
                           const float* __restrict__ y, const float* __restrict__ svec,
                           float* __restrict__ pout) {
    int idx = blockIdx.x * 256 + threadIdx.x;   // exact 153600
    int t = idx / NSC;
    int sc = idx - t*NSC;
    float s0 = svec[0], s1 = svec[1], s2 = svec[2], s3 = svec[3];
    float z = 0.f, w = 0.f;
    #pragma unroll
    for (int tp = 0; tp < TT; ++tp) {
        float a = At_n[t*TT + tp];
        z += a * p[tp*NSC + sc];
        w += a * y[tp*NSC + sc];
    }
    pout[idx] = s0*p[idx] + s1*y[idx] + s2*z + s3*w;
}

// ---------------- epilogue: acc = x@H0+p1@H1+p2@H2; xt=tanh; MLP ----------------
__global__ void k_epilogue(const float* __restrict__ x, const float* __restrict__ p1,
                           const float* __restrict__ p2, const float* __restrict__ xin,
                           const float* __restrict__ Hb,     // 3*32*32
                           const float* __restrict__ W1,     // 40*32
                           const float* __restrict__ b1,     // 32
                           const float* __restrict__ W2,     // 32*32
                           const float* __restrict__ b2,     // 32
                           float* __restrict__ xout) {
    __shared__ float sH[3*CW*CW];     // 3072
    __shared__ float sW1[40*CW];      // 1280
    __shared__ float sW2[CW*CW];      // 1024
    __shared__ float sb1[CW], sb2[CW];
    __shared__ float sx[8][CW], sp1[8][CW], sp2[8][CW], sxin[8][CIN];
    __shared__ float sxt[8][CW], sh[8][CW];

    int tid = threadIdx.x;
    for (int i = tid; i < 3*CW*CW; i += 256) sH[i]  = Hb[i];
    for (int i = tid; i < 40*CW;   i += 256) sW1[i] = W1[i];
    for (int i = tid; i < CW*CW;   i += 256) sW2[i] = W2[i];
    if (tid < CW) { sb1[tid] = b1[tid]; sb2[tid] = b2[tid]; }

    int r = tid >> 5, c = tid & 31;
    int n = blockIdx.x * 8 + r;
    sx[r][c]  = x[n*CW + c];
    sp1[r][c] = p1[n*CW + c];
    sp2[r][c] = p2[n*CW + c];
    if (c < CIN) sxin[r][c] = xin[n*CIN + c];
    __syncthreads();

    float acc = 0.f;
    #pragma unroll 8
    for (int cp = 0; cp < CW; ++cp) {
        acc += sx[r][cp]  * sH[cp*CW + c];
        acc += sp1[r][cp] * sH[CW*CW + cp*CW + c];
        acc += sp2[r][cp] * sH[2*CW*CW + cp*CW + c];
    }
    sxt[r][c] = tanhf(acc);
    __syncthreads();

    float hacc = sb1[c];
    #pragma unroll 8
    for (int cp = 0; cp < CW; ++cp) hacc += sxt[r][cp] * sW1[cp*CW + c];
    #pragma unroll
    for (int i = 0; i < CIN; ++i) hacc += sxin[r][i] * sW1[(CW+i)*CW + c];
    sh[r][c] = fmaxf(hacc, 0.f);
    __syncthreads();

    float xn = sb2[c];
    #pragma unroll 8
    for (int cp = 0; cp < CW; ++cp) xn += sh[r][cp] * sW2[cp*CW + c];
    xout[n*CW + c] = xn;
}

// ---------------- out = x @ W_last + b_last ----------------
__global__ void k_last(const float* __restrict__ x, const float* __restrict__ Wl,
                       const float* __restrict__ bl, float* __restrict__ out) {
    int idx = blockIdx.x * 256 + threadIdx.x;  // exact 153600
    int n = idx >> 5, c = idx & 31;
    float v = x[idx] * Wl[c];
    #pragma unroll
    for (int off = 16; off; off >>= 1) v += __shfl_xor(v, off, 64);
    if (c == 0) out[n] = v + bl[0];
}

extern "C" void kernel_launch(void* const* d_in, const int* in_sizes, int n_in,
                              void* d_out, int out_size, void* d_ws, size_t ws_size,
                              hipStream_t stream) {
    const float* xin    = (const float*)d_in[0];   // [4800,8]
    const float* Adj_t  = (const float*)d_in[1];   // [24,24]
    const float* Adj_s  = (const float*)d_in[2];   // [200,200]
    const float* H      = (const float*)d_in[3];   // [2,3,32,32]
    const float* svec   = (const float*)d_in[4];   // [2,4]
    const float* Wf     = (const float*)d_in[5];   // [8,32]
    const float* bf     = (const float*)d_in[6];   // [32]
    const float* Wl     = (const float*)d_in[7];   // [32,1]
    const float* bl     = (const float*)d_in[8];   // [1]
    const float* mW1    = (const float*)d_in[9];   // [2,40,32]
    const float* mb1    = (const float*)d_in[10];  // [2,32]
    const float* mW2    = (const float*)d_in[11];  // [2,32,32]
    const float* mb2    = (const float*)d_in[12];  // [2,32]
    float* out = (float*)d_out;

    float* ws = (float*)d_ws;
    float* dinv_t = ws;            // 24
    float* dinv_s = ws + 32;       // 200
    float* At_n   = ws + 256;      // 576
    float* As_n   = ws + 1024;     // 40000
    float* X      = ws + 41024;    // 153600
    float* Y      = X  + 153600;
    float* P1     = Y  + 153600;
    float* P2     = P1 + 153600;   // total ~2.62 MB

    k_dinv<<<1, 256, 0, stream>>>(Adj_t, Adj_s, dinv_t, dinv_s);
    k_norm<<<159, 256, 0, stream>>>(Adj_t, Adj_s, dinv_t, dinv_s, At_n, As_n);
    k_first<<<600, 256, 0, stream>>>(xin, Wf, bf, X);

    for (int b = 0; b < 2; ++b) {
        const float* sb = svec + b*4;
        k_spatial<<<600, 256, 0, stream>>>(As_n, X, Y);
        k_temporal<<<600, 256, 0, stream>>>(At_n, X, Y, sb, P1);
        k_spatial<<<600, 256, 0, stream>>>(As_n, P1, Y);
        k_temporal<<<600, 256, 0, stream>>>(At_n, P1, Y, sb, P2);
        k_epilogue<<<600, 256, 0, stream>>>(X, P1, P2, xin,
                                            H + b*3*CW*CW,
                                            mW1 + b*40*CW, mb1 + b*CW,
                                            mW2 + b*CW*CW, mb2 + b*CW,
                                            X);
    }
    k_last<<<600, 256, 0, stream>>>(X, Wl, bl, out);
}